// Round 2
// baseline (1023.578 us; speedup 1.0000x reference)
//
#include <hip/hip_runtime.h>
#include <hip/hip_bf16.h>
#include <cstdio>

using bf16 = __hip_bfloat16;
typedef __attribute__((ext_vector_type(8))) __bf16 bf16x8;
typedef __attribute__((ext_vector_type(4))) float f32x4;

#define DI static __device__ __forceinline__

DI f32x4 mfma16(bf16x8 a, bf16x8 b, f32x4 c) {
  return __builtin_amdgcn_mfma_f32_16x16x32_bf16(a, b, c, 0, 0, 0);
}

// async global->LDS, 16B per lane. LDS dest must be wave-uniform base (HW adds lane*16).
DI void gload16(const bf16* g, bf16* lds_base) {
  __builtin_amdgcn_global_load_lds(
      (const __attribute__((address_space(1))) unsigned int*)g,
      (__attribute__((address_space(3))) unsigned int*)lds_base,
      16, 0, 0);
}

DI bf16x8 ld8(const bf16* p) { return *(const bf16x8*)p; }

// ---------------- fp32 -> bf16 cast (vectorized) ----------------
__global__ __launch_bounds__(256) void cast_bf16_kernel(const float* __restrict__ in,
                                                        bf16* __restrict__ out, int n4) {
  int i = blockIdx.x * 256 + threadIdx.x;
  if (i >= n4) return;
  float4 v = reinterpret_cast<const float4*>(in)[i];
  bf16 o4[4] = {__float2bfloat16(v.x), __float2bfloat16(v.y),
                __float2bfloat16(v.z), __float2bfloat16(v.w)};
  reinterpret_cast<ushort4*>(out)[i] = *reinterpret_cast<ushort4*>(o4);
}

// ---------------- bf16 GEMM: C[M,N] = A[M,K] * B[N,K]^T ----------------
// m97 structure: 128x128 tile, BK=64, 4 waves (2x2), global_load_lds w=16,
// XOR chunk-swizzle (pre-swizzled global source + swizzled ds_read).
template<int OUT_F32>
__global__ __launch_bounds__(256) void gemm_bt(const bf16* __restrict__ A,
                                               const bf16* __restrict__ B,
                                               void* __restrict__ Cout,
                                               int M, int N, int K) {
  __shared__ bf16 As[128 * 64];
  __shared__ bf16 Bs[128 * 64];
  const int lane = threadIdx.x & 63;
  const int wave = threadIdx.x >> 6;
  const int wm = wave >> 1, wn = wave & 1;
  const int row0 = blockIdx.y * 128;
  const int col0 = blockIdx.x * 128;
  const int l4 = lane >> 4, l15 = lane & 15;
  const int lr = lane >> 3, lc = lane & 7;

  f32x4 acc[4][4] = {};

  for (int k0 = 0; k0 < K; k0 += 64) {
#pragma unroll
    for (int i = 0; i < 4; ++i) {
      const int seg = wave * 4 + i;          // 16 x 1KB segments per tile
      const int r = seg * 8 + lr;            // 8 rows (128B each) per segment
      const int cg = lc ^ (r & 7);           // inverse-swizzled global chunk
      gload16(A + (size_t)(row0 + r) * K + k0 + cg * 8, As + seg * 512);
      gload16(B + (size_t)(col0 + r) * K + k0 + cg * 8, Bs + seg * 512);
    }
    __syncthreads();
#pragma unroll
    for (int kk = 0; kk < 2; ++kk) {
      bf16x8 af[4], bfr[4];
#pragma unroll
      for (int mi = 0; mi < 4; ++mi) {
        const int r = wm * 64 + mi * 16 + l15;
        const int ch = (kk * 4 + l4) ^ (r & 7);
        af[mi] = ld8(As + r * 64 + ch * 8);
      }
#pragma unroll
      for (int ni = 0; ni < 4; ++ni) {
        const int r = wn * 64 + ni * 16 + l15;
        const int ch = (kk * 4 + l4) ^ (r & 7);
        bfr[ni] = ld8(Bs + r * 64 + ch * 8);
      }
#pragma unroll
      for (int mi = 0; mi < 4; ++mi)
#pragma unroll
        for (int ni = 0; ni < 4; ++ni)
          acc[mi][ni] = mfma16(af[mi], bfr[ni], acc[mi][ni]);
    }
    __syncthreads();
  }
#pragma unroll
  for (int mi = 0; mi < 4; ++mi)
#pragma unroll
    for (int ni = 0; ni < 4; ++ni) {
      const int r0 = row0 + wm * 64 + mi * 16 + l4 * 4;
      const int c = col0 + wn * 64 + ni * 16 + l15;
#pragma unroll
      for (int j = 0; j < 4; ++j) {
        if (OUT_F32)
          ((float*)Cout)[(size_t)(r0 + j) * N + c] = acc[mi][ni][j];
        else
          ((bf16*)Cout)[(size_t)(r0 + j) * N + c] = __float2bfloat16(acc[mi][ni][j]);
      }
    }
}

// ---------------- V transpose: Vp[b,s,h*128+d] -> Vt[(b*H+h)*128+d, s] ----------------
__global__ __launch_bounds__(256) void transpose_v(const bf16* __restrict__ Vp,
                                                   bf16* __restrict__ Vt) {
  constexpr int S = 2048, D = 2048, Dk = 128;
  __shared__ bf16 t[32][33];
  const int bh = blockIdx.z;
  const int b = bh >> 4, h = bh & 15;
  const int s0 = blockIdx.x * 32, d0 = blockIdx.y * 32;
  const int tx = threadIdx.x, ty = threadIdx.y;
#pragma unroll
  for (int j = 0; j < 4; ++j)
    t[ty + j * 8][tx] = Vp[(size_t)(b * S + s0 + ty + j * 8) * D + h * Dk + d0 + tx];
  __syncthreads();
#pragma unroll
  for (int j = 0; j < 4; ++j)
    Vt[(size_t)(bh * Dk + d0 + ty + j * 8) * S + s0 + tx] = t[tx][ty + j * 8];
}

// ---------------- flash attention ----------------
// grid: (S/128, B*H). block: 256 (4 waves x 32 Q-rows). KV tile = 64.
__global__ __launch_bounds__(256) void attn_fwd(const bf16* __restrict__ Qp,
                                                const bf16* __restrict__ Kp,
                                                const bf16* __restrict__ Vt,
                                                bf16* __restrict__ ctx) {
  constexpr int S = 2048, D = 2048, Dk = 128;
  constexpr float scale = 0.08838834764831845f;  // 1/sqrt(128)
  __shared__ bf16 Ks[64 * 128];
  __shared__ bf16 Vs[128 * 64];
  __shared__ bf16 Ps[4][32 * 64];
  const int lane = threadIdx.x & 63;
  const int wave = threadIdx.x >> 6;
  const int bh = blockIdx.y, b = bh >> 4, h = bh & 15;
  const int qt = blockIdx.x;
  const int l4 = lane >> 4, l15 = lane & 15;

  // hoist Q fragments (per wave: 32 rows x 128 dk)
  bf16x8 qf[2][4];
  {
    const bf16* Qb = Qp + (size_t)(b * S + qt * 128 + wave * 32) * D + h * Dk;
#pragma unroll
    for (int mi = 0; mi < 2; ++mi)
#pragma unroll
      for (int kf = 0; kf < 4; ++kf)
        qf[mi][kf] = ld8(Qb + (size_t)(mi * 16 + l15) * D + kf * 32 + l4 * 8);
  }

  f32x4 acc[2][8] = {};
  float mrow[2][4], lrow[2][4];
#pragma unroll
  for (int mi = 0; mi < 2; ++mi)
#pragma unroll
    for (int j = 0; j < 4; ++j) { mrow[mi][j] = -1e30f; lrow[mi][j] = 0.f; }

  for (int s0 = 0; s0 < S; s0 += 64) {
#pragma unroll
    for (int i = 0; i < 4; ++i) {
      const int seg = wave * 4 + i;
      {  // K tile [64 s][128 dk], 4 rows (256B) per 1KB segment
        const int r = seg * 4 + l4;
        const int cg = l15 ^ (r & 7);
        gload16(Kp + (size_t)(b * S + s0 + r) * D + h * Dk + cg * 8, Ks + seg * 512);
      }
      {  // V tile [128 d][64 s], 8 rows (128B) per segment
        const int d = seg * 8 + (lane >> 3);
        const int cg = (lane & 7) ^ (d & 7);
        gload16(Vt + (size_t)(bh * Dk + d) * S + s0 + cg * 8, Vs + seg * 512);
      }
    }
    __syncthreads();

    // S = Q * K^T (per wave: 32 q x 64 k)
    f32x4 sc[2][4] = {};
#pragma unroll
    for (int kf = 0; kf < 4; ++kf) {
      bf16x8 kb[4];
#pragma unroll
      for (int ni = 0; ni < 4; ++ni) {
        const int r = ni * 16 + l15;
        const int ch = (kf * 4 + l4) ^ (r & 7);
        kb[ni] = ld8(Ks + r * 128 + ch * 8);
      }
#pragma unroll
      for (int mi = 0; mi < 2; ++mi)
#pragma unroll
        for (int ni = 0; ni < 4; ++ni)
          sc[mi][ni] = mfma16(qf[mi][kf], kb[ni], sc[mi][ni]);
    }

    // online softmax (row = (lane>>4)*4+j + mi*16; cols across 16 lanes x 4 ni)
    float corr[2][4];
#pragma unroll
    for (int mi = 0; mi < 2; ++mi)
#pragma unroll
      for (int j = 0; j < 4; ++j) {
        float vm = -1e30f;
#pragma unroll
        for (int ni = 0; ni < 4; ++ni) {
          sc[mi][ni][j] *= scale;
          vm = fmaxf(vm, sc[mi][ni][j]);
        }
#pragma unroll
        for (int off = 1; off < 16; off <<= 1)
          vm = fmaxf(vm, __shfl_xor(vm, off));
        const float mnew = fmaxf(mrow[mi][j], vm);
        const float cr = __expf(mrow[mi][j] - mnew);
        mrow[mi][j] = mnew;
        float rs = 0.f;
#pragma unroll
        for (int ni = 0; ni < 4; ++ni) {
          const float p = __expf(sc[mi][ni][j] - mnew);
          sc[mi][ni][j] = p;
          rs += p;
        }
#pragma unroll
        for (int off = 1; off < 16; off <<= 1)
          rs += __shfl_xor(rs, off);
        lrow[mi][j] = lrow[mi][j] * cr + rs;
        corr[mi][j] = cr;
      }
#pragma unroll
    for (int mi = 0; mi < 2; ++mi)
#pragma unroll
      for (int di = 0; di < 8; ++di)
#pragma unroll
        for (int j = 0; j < 4; ++j)
          acc[mi][di][j] *= corr[mi][j];

    // P -> LDS (per-wave buffer, swizzled), then PV
    bf16* Pw = &Ps[wave][0];
#pragma unroll
    for (int mi = 0; mi < 2; ++mi)
#pragma unroll
      for (int ni = 0; ni < 4; ++ni)
#pragma unroll
        for (int j = 0; j < 4; ++j) {
          const int row = mi * 16 + l4 * 4 + j;
          const int col = (ni * 16 + l15) ^ ((row & 7) << 3);
          Pw[row * 64 + col] = __float2bfloat16(sc[mi][ni][j]);
        }
#pragma unroll
    for (int kk = 0; kk < 2; ++kk) {
      bf16x8 pa[2];
#pragma unroll
      for (int mi = 0; mi < 2; ++mi) {
        const int r = mi * 16 + l15;
        const int ch = (kk * 4 + l4) ^ (r & 7);
        pa[mi] = ld8(Pw + r * 64 + ch * 8);
      }
#pragma unroll
      for (int di = 0; di < 8; ++di) {
        const int r = di * 16 + l15;
        const int ch = (kk * 4 + l4) ^ (r & 7);
        const bf16x8 vb = ld8(Vs + r * 64 + ch * 8);
#pragma unroll
        for (int mi = 0; mi < 2; ++mi)
          acc[mi][di] = mfma16(pa[mi], vb, acc[mi][di]);
      }
    }
    __syncthreads();
  }

  // epilogue: O = acc / l  -> ctx[b,s,h*128+d] (bf16)
#pragma unroll
  for (int mi = 0; mi < 2; ++mi)
#pragma unroll
    for (int j = 0; j < 4; ++j) {
      const float inv = 1.f / lrow[mi][j];
      const size_t base =
          (size_t)(b * S + qt * 128 + wave * 32 + mi * 16 + l4 * 4 + j) * D + h * Dk + l15;
#pragma unroll
      for (int di = 0; di < 8; ++di)
        ctx[base + di * 16] = __float2bfloat16(acc[mi][di][j] * inv);
    }
}

// ---------------- host orchestration ----------------
extern "C" void kernel_launch(void* const* d_in, const int* in_sizes, int n_in,
                              void* d_out, int out_size, void* d_ws, size_t ws_size,
                              hipStream_t stream) {
  constexpr int B = 4, S = 2048, D = 2048, H = 16, Dk = 128;
  constexpr size_t MD = (size_t)B * S * D;  // 16.8M elems
  constexpr size_t DD = (size_t)D * D;      // 4.2M elems

  const float* q  = (const float*)d_in[0];
  const float* k  = (const float*)d_in[1];
  const float* v  = (const float*)d_in[2];
  const float* wq = (const float*)d_in[3];
  const float* wk = (const float*)d_in[4];
  const float* wv = (const float*)d_in[5];
  const float* wo = (const float*)d_in[6];

  // Lean workspace layout (~109 MB in d_ws; Qp/Kp live inside d_out's 64 MiB,
  // both dead before the final GEMM overwrites d_out with fp32 results).
  bf16* ws = (bf16*)d_ws;
  bf16* xb = ws + 0 * MD;   // cast buffer for q/k/v (sequential), later ctx
  bf16* Vp = ws + 1 * MD;
  bf16* Vt = ws + 2 * MD;
  bf16* wb = ws + 3 * MD;   // cast buffer for wq/wk/wv/wo (sequential), DD elems
  bf16* Qp = (bf16*)d_out;  // 2*MD bf16 == 64 MiB == out_size fp32 exactly
  bf16* Kp = Qp + MD;

  const size_t need = (3 * MD + DD) * sizeof(bf16);
  if (ws_size < need)
    fprintf(stderr, "kernel_launch: ws too small (%zu < %zu)\n", ws_size, need);

  auto cast = [&](const float* src, bf16* dst, size_t n) {
    const int n4 = (int)(n / 4);
    cast_bf16_kernel<<<dim3((n4 + 255) / 256), dim3(256), 0, stream>>>(src, dst, n4);
  };
  const dim3 gg(D / 128, (B * S) / 128);

  // Q projection
  cast(q, xb, MD);
  cast(wq, wb, DD);
  gemm_bt<0><<<gg, dim3(256), 0, stream>>>(xb, wb, Qp, B * S, D, D);
  // K projection
  cast(k, xb, MD);
  cast(wk, wb, DD);
  gemm_bt<0><<<gg, dim3(256), 0, stream>>>(xb, wb, Kp, B * S, D, D);
  // V projection
  cast(v, xb, MD);
  cast(wv, wb, DD);
  gemm_bt<0><<<gg, dim3(256), 0, stream>>>(xb, wb, Vp, B * S, D, D);

  transpose_v<<<dim3(S / 32, Dk / 32, B * H), dim3(32, 8), 0, stream>>>(Vp, Vt);

  bf16* ctx = xb;
  attn_fwd<<<dim3(S / 128, B * H), dim3(256), 0, stream>>>(Qp, Kp, Vt, ctx);

  // O projection (fp32 out)
  cast(wo, wb, DD);
  gemm_bt<1><<<gg, dim3(256), 0, stream>>>(ctx, wb, d_out, B * S, D, D);
}

// Round 4
// 953.329 us; speedup vs baseline: 1.0737x; 1.0737x over previous
//
#include <hip/hip_runtime.h>
#include <hip/hip_bf16.h>
#include <cstdio>

using bf16 = __hip_bfloat16;
typedef __attribute__((ext_vector_type(8))) __bf16 bf16x8;
typedef __attribute__((ext_vector_type(4))) float f32x4;

#define DI static __device__ __forceinline__

DI f32x4 mfma16(bf16x8 a, bf16x8 b, f32x4 c) {
  return __builtin_amdgcn_mfma_f32_16x16x32_bf16(a, b, c, 0, 0, 0);
}

// async global->LDS, 16B per lane. LDS dest must be wave-uniform base (HW adds lane*16).
DI void gload16(const bf16* g, bf16* lds_base) {
  __builtin_amdgcn_global_load_lds(
      (const __attribute__((address_space(1))) unsigned int*)g,
      (__attribute__((address_space(3))) unsigned int*)lds_base,
      16, 0, 0);
}

DI bf16x8 ld8(const bf16* p) { return *(const bf16x8*)p; }

DI unsigned pack_bf16(float lo, float hi) {
  bf16 l = __float2bfloat16(lo), h = __float2bfloat16(hi);
  unsigned short ul = *(unsigned short*)&l, uh = *(unsigned short*)&h;
  return ((unsigned)uh << 16) | (unsigned)ul;
}

// ---------------- fp32 -> bf16 cast (vectorized) ----------------
__global__ __launch_bounds__(256) void cast_bf16_kernel(const float* __restrict__ in,
                                                        bf16* __restrict__ out, int n4) {
  int i = blockIdx.x * 256 + threadIdx.x;
  if (i >= n4) return;
  float4 v = reinterpret_cast<const float4*>(in)[i];
  bf16 o4[4] = {__float2bfloat16(v.x), __float2bfloat16(v.y),
                __float2bfloat16(v.z), __float2bfloat16(v.w)};
  reinterpret_cast<ushort4*>(out)[i] = *reinterpret_cast<ushort4*>(o4);
}

// ---------------- bf16 GEMM: C[M,N] = A[M,K] * B[N,K]^T ----------------
// m97 structure: 128x128 tile, BK=64, 4 waves (2x2), global_load_lds w=16,
// XOR chunk-swizzle (pre-swizzled global source + swizzled ds_read).
template<int OUT_F32>
__global__ __launch_bounds__(256) void gemm_bt(const bf16* __restrict__ A,
                                               const bf16* __restrict__ B,
                                               void* __restrict__ Cout,
                                               int M, int N, int K) {
  __shared__ bf16 As[128 * 64];
  __shared__ bf16 Bs[128 * 64];
  const int lane = threadIdx.x & 63;
  const int wave = threadIdx.x >> 6;
  const int wm = wave >> 1, wn = wave & 1;
  const int row0 = blockIdx.y * 128;
  const int col0 = blockIdx.x * 128;
  const int l4 = lane >> 4, l15 = lane & 15;
  const int lr = lane >> 3, lc = lane & 7;

  f32x4 acc[4][4] = {};

  for (int k0 = 0; k0 < K; k0 += 64) {
#pragma unroll
    for (int i = 0; i < 4; ++i) {
      const int seg = wave * 4 + i;          // 16 x 1KB segments per tile
      const int r = seg * 8 + lr;            // 8 rows (128B each) per segment
      const int cg = lc ^ (r & 7);           // inverse-swizzled global chunk
      gload16(A + (size_t)(row0 + r) * K + k0 + cg * 8, As + seg * 512);
      gload16(B + (size_t)(col0 + r) * K + k0 + cg * 8, Bs + seg * 512);
    }
    __syncthreads();
#pragma unroll
    for (int kk = 0; kk < 2; ++kk) {
      bf16x8 af[4], bfr[4];
#pragma unroll
      for (int mi = 0; mi < 4; ++mi) {
        const int r = wm * 64 + mi * 16 + l15;
        const int ch = (kk * 4 + l4) ^ (r & 7);
        af[mi] = ld8(As + r * 64 + ch * 8);
      }
#pragma unroll
      for (int ni = 0; ni < 4; ++ni) {
        const int r = wn * 64 + ni * 16 + l15;
        const int ch = (kk * 4 + l4) ^ (r & 7);
        bfr[ni] = ld8(Bs + r * 64 + ch * 8);
      }
#pragma unroll
      for (int mi = 0; mi < 4; ++mi)
#pragma unroll
        for (int ni = 0; ni < 4; ++ni)
          acc[mi][ni] = mfma16(af[mi], bfr[ni], acc[mi][ni]);
    }
    __syncthreads();
  }
#pragma unroll
  for (int mi = 0; mi < 4; ++mi)
#pragma unroll
    for (int ni = 0; ni < 4; ++ni) {
      const int r0 = row0 + wm * 64 + mi * 16 + l4 * 4;
      const int c = col0 + wn * 64 + ni * 16 + l15;
#pragma unroll
      for (int j = 0; j < 4; ++j) {
        if (OUT_F32)
          ((float*)Cout)[(size_t)(r0 + j) * N + c] = acc[mi][ni][j];
        else
          ((bf16*)Cout)[(size_t)(r0 + j) * N + c] = __float2bfloat16(acc[mi][ni][j]);
      }
    }
}

// ---------------- V transpose: Vp[b,s,h*128+d] -> Vt[(b*H+h)*128+d, s] ----------------
__global__ __launch_bounds__(256) void transpose_v(const bf16* __restrict__ Vp,
                                                   bf16* __restrict__ Vt) {
  constexpr int S = 2048, D = 2048, Dk = 128;
  __shared__ bf16 t[32][33];
  const int bh = blockIdx.z;
  const int b = bh >> 4, h = bh & 15;
  const int s0 = blockIdx.x * 32, d0 = blockIdx.y * 32;
  const int tx = threadIdx.x, ty = threadIdx.y;
#pragma unroll
  for (int j = 0; j < 4; ++j)
    t[ty + j * 8][tx] = Vp[(size_t)(b * S + s0 + ty + j * 8) * D + h * Dk + d0 + tx];
  __syncthreads();
#pragma unroll
  for (int j = 0; j < 4; ++j)
    Vt[(size_t)(bh * Dk + d0 + ty + j * 8) * S + s0 + tx] = t[tx][ty + j * 8];
}

// ---------------- flash attention v2 ----------------
// Swapped QK^T (lane-local q rows), in-register softmax, packed P->LDS (b64),
// defer-rescale (T13), setprio (T5). grid: (S/128, B*H), 4 waves x 32 q-rows.
__global__ __launch_bounds__(256, 3) void attn_fwd(const bf16* __restrict__ Qp,
                                                   const bf16* __restrict__ Kp,
                                                   const bf16* __restrict__ Vt,
                                                   bf16* __restrict__ ctx) {
  constexpr int S = 2048, D = 2048, Dk = 128;
  constexpr float scale = 0.08838834764831845f;  // 1/sqrt(128)
  constexpr float DEFER_THR = 90.50966799187809f;  // 8/scale (raw-score domain)
  __shared__ bf16 Ks[64 * 128];
  __shared__ bf16 Vs[128 * 64];
  __shared__ bf16 Ps[4][32 * 64];
  const int lane = threadIdx.x & 63;
  const int wave = threadIdx.x >> 6;
  const int bh = blockIdx.y, b = bh >> 4, h = bh & 15;
  const int qt = blockIdx.x;
  const int l4 = lane >> 4, l15 = lane & 15;

  // hoist Q fragments: B-operand layout, Q[q = mi*16+l15][dk = kf*32 + l4*8 + 0..7]
  bf16x8 qf[2][4];
  {
    const bf16* Qb = Qp + (size_t)(b * S + qt * 128 + wave * 32) * D + h * Dk;
#pragma unroll
    for (int mi = 0; mi < 2; ++mi)
#pragma unroll
      for (int kf = 0; kf < 4; ++kf)
        qf[mi][kf] = ld8(Qb + (size_t)(mi * 16 + l15) * D + kf * 32 + l4 * 8);
  }

  f32x4 acc[2][8] = {};
  float mrow[2] = {-1e30f, -1e30f};  // raw-score running max for q = mi*16+l15
  float lrow[2] = {0.f, 0.f};

  bf16* Pw = &Ps[wave][0];

  for (int s0 = 0; s0 < S; s0 += 64) {
#pragma unroll
    for (int i = 0; i < 4; ++i) {
      const int seg = wave * 4 + i;
      {  // K tile [64 s][128 dk], 4 rows (256B) per 1KB segment
        const int r = seg * 4 + l4;
        const int cg = l15 ^ (r & 7);
        gload16(Kp + (size_t)(b * S + s0 + r) * D + h * Dk + cg * 8, Ks + seg * 512);
      }
      {  // V tile [128 d][64 s], 8 rows (128B) per segment
        const int d = seg * 8 + (lane >> 3);
        const int cg = (lane & 7) ^ (d & 7);
        gload16(Vt + (size_t)(bh * Dk + d) * S + s0 + cg * 8, Vs + seg * 512);
      }
    }
    __syncthreads();

    // S^T = K * Q^T : sc[ni][mi] holds S[q = mi*16+l15][k = ni*16 + l4*4 + j]
    f32x4 sc[4][2] = {};
    __builtin_amdgcn_s_setprio(1);
#pragma unroll
    for (int kf = 0; kf < 4; ++kf) {
      bf16x8 kb[4];
#pragma unroll
      for (int ni = 0; ni < 4; ++ni) {
        const int r = ni * 16 + l15;
        const int ch = (kf * 4 + l4) ^ (r & 7);
        kb[ni] = ld8(Ks + r * 128 + ch * 8);
      }
#pragma unroll
      for (int ni = 0; ni < 4; ++ni)
#pragma unroll
        for (int mi = 0; mi < 2; ++mi)
          sc[ni][mi] = mfma16(kb[ni], qf[mi][kf], sc[ni][mi]);
    }
    __builtin_amdgcn_s_setprio(0);

    // per-q tile max (raw domain): 15 in-register + 2 shuffles
    float vm[2];
#pragma unroll
    for (int mi = 0; mi < 2; ++mi) {
      float a = fmaxf(fmaxf(sc[0][mi][0], sc[0][mi][1]), fmaxf(sc[0][mi][2], sc[0][mi][3]));
#pragma unroll
      for (int ni = 1; ni < 4; ++ni) {
        a = fmaxf(a, fmaxf(fmaxf(sc[ni][mi][0], sc[ni][mi][1]),
                           fmaxf(sc[ni][mi][2], sc[ni][mi][3])));
      }
      a = fmaxf(a, __shfl_xor(a, 16));
      a = fmaxf(a, __shfl_xor(a, 32));
      vm[mi] = a;
    }

    // T13 defer-rescale: only rescale when tile max grew past threshold
    const int ok = (vm[0] - mrow[0] <= DEFER_THR) && (vm[1] - mrow[1] <= DEFER_THR);
    if (!__all(ok)) {
#pragma unroll
      for (int mi = 0; mi < 2; ++mi) {
        const float mnew = fmaxf(mrow[mi], vm[mi]);
        const float cr = __expf((mrow[mi] - mnew) * scale);
        mrow[mi] = mnew;
        lrow[mi] *= cr;
        // redistribute cr to acc's q-domain (q = mi*16 + l4*4 + j)
        float crd[4];
#pragma unroll
        for (int j = 0; j < 4; ++j) crd[j] = __shfl(cr, l4 * 4 + j);
#pragma unroll
        for (int di = 0; di < 8; ++di)
#pragma unroll
          for (int j = 0; j < 4; ++j) acc[mi][di][j] *= crd[j];
      }
    }

    // P = exp((s - m)*scale), row-sum, pack to bf16 pairs, store via ds_write_b64
#pragma unroll
    for (int mi = 0; mi < 2; ++mi) {
      const float nms = -mrow[mi] * scale;
      float rs = 0.f;
      const int q_local = mi * 16 + l15;
#pragma unroll
      for (int ni = 0; ni < 4; ++ni) {
        float p0 = __expf(fmaf(sc[ni][mi][0], scale, nms));
        float p1 = __expf(fmaf(sc[ni][mi][1], scale, nms));
        float p2 = __expf(fmaf(sc[ni][mi][2], scale, nms));
        float p3 = __expf(fmaf(sc[ni][mi][3], scale, nms));
        rs += (p0 + p1) + (p2 + p3);
        uint2 w;
        w.x = pack_bf16(p0, p1);
        w.y = pack_bf16(p2, p3);
        const int c16 = (ni * 2 + (l4 >> 1)) ^ (q_local & 7);
        *reinterpret_cast<uint2*>(Pw + q_local * 64 + c16 * 8 + (l4 & 1) * 4) = w;
      }
      rs += __shfl_xor(rs, 16);
      rs += __shfl_xor(rs, 32);
      lrow[mi] += rs;
    }

    // PV: O[q][d] += P[q][k] V[k][d]
    __builtin_amdgcn_s_setprio(1);
#pragma unroll
    for (int kk = 0; kk < 2; ++kk) {
      bf16x8 pa[2];
#pragma unroll
      for (int mi = 0; mi < 2; ++mi) {
        const int q_local = mi * 16 + l15;
        const int c = (kk * 4 + l4) ^ (q_local & 7);
        pa[mi] = ld8(Pw + q_local * 64 + c * 8);
      }
#pragma unroll
      for (int di = 0; di < 8; ++di) {
        const int r = di * 16 + l15;
        const int ch = (kk * 4 + l4) ^ (r & 7);
        const bf16x8 vb = ld8(Vs + r * 64 + ch * 8);
#pragma unroll
        for (int mi = 0; mi < 2; ++mi)
          acc[mi][di] = mfma16(pa[mi], vb, acc[mi][di]);
      }
    }
    __builtin_amdgcn_s_setprio(0);
    __syncthreads();
  }

  // epilogue: O = acc / l  -> ctx[b,s,h*128+d] (bf16); acc q = mi*16+l4*4+j, d = di*16+l15
#pragma unroll
  for (int mi = 0; mi < 2; ++mi) {
    float invd[4];
#pragma unroll
    for (int j = 0; j < 4; ++j) invd[j] = 1.f / __shfl(lrow[mi], l4 * 4 + j);
#pragma unroll
    for (int j = 0; j < 4; ++j) {
      const size_t base =
          (size_t)(b * S + qt * 128 + wave * 32 + mi * 16 + l4 * 4 + j) * D + h * Dk + l15;
#pragma unroll
      for (int di = 0; di < 8; ++di)
        ctx[base + di * 16] = __float2bfloat16(acc[mi][di][j] * invd[j]);
    }
  }
}

// ---------------- host orchestration ----------------
extern "C" void kernel_launch(void* const* d_in, const int* in_sizes, int n_in,
                              void* d_out, int out_size, void* d_ws, size_t ws_size,
                              hipStream_t stream) {
  constexpr int B = 4, S = 2048, D = 2048, H = 16, Dk = 128;
  constexpr size_t MD = (size_t)B * S * D;  // 16.8M elems
  constexpr size_t DD = (size_t)D * D;      // 4.2M elems

  const float* q  = (const float*)d_in[0];
  const float* k  = (const float*)d_in[1];
  const float* v  = (const float*)d_in[2];
  const float* wq = (const float*)d_in[3];
  const float* wk = (const float*)d_in[4];
  const float* wv = (const float*)d_in[5];
  const float* wo = (const float*)d_in[6];

  // Lean workspace layout (~109 MB in d_ws; Qp/Kp live inside d_out's 64 MiB,
  // both dead before the final GEMM overwrites d_out with fp32 results).
  bf16* ws = (bf16*)d_ws;
  bf16* xb = ws + 0 * MD;   // cast buffer for q/k/v (sequential), later ctx
  bf16* Vp = ws + 1 * MD;
  bf16* Vt = ws + 2 * MD;
  bf16* wb = ws + 3 * MD;   // cast buffer for wq/wk/wv/wo (sequential), DD elems
  bf16* Qp = (bf16*)d_out;  // 2*MD bf16 == 64 MiB == out_size fp32 exactly
  bf16* Kp = Qp + MD;

  const size_t need = (3 * MD + DD) * sizeof(bf16);
  if (ws_size < need)
    fprintf(stderr, "kernel_launch: ws too small (%zu < %zu)\n", ws_size, need);

  auto cast = [&](const float* src, bf16* dst, size_t n) {
    const int n4 = (int)(n / 4);
    cast_bf16_kernel<<<dim3((n4 + 255) / 256), dim3(256), 0, stream>>>(src, dst, n4);
  };
  const dim3 gg(D / 128, (B * S) / 128);

  // Q projection
  cast(q, xb, MD);
  cast(wq, wb, DD);
  gemm_bt<0><<<gg, dim3(256), 0, stream>>>(xb, wb, Qp, B * S, D, D);
  // K projection
  cast(k, xb, MD);
  cast(wk, wb, DD);
  gemm_bt<0><<<gg, dim3(256), 0, stream>>>(xb, wb, Kp, B * S, D, D);
  // V projection
  cast(v, xb, MD);
  cast(wv, wb, DD);
  gemm_bt<0><<<gg, dim3(256), 0, stream>>>(xb, wb, Vp, B * S, D, D);

  transpose_v<<<dim3(S / 32, Dk / 32, B * H), dim3(32, 8), 0, stream>>>(Vp, Vt);

  bf16* ctx = xb;
  attn_fwd<<<dim3(S / 128, B * H), dim3(256), 0, stream>>>(Qp, Kp, Vt, ctx);

  // O projection (fp32 out)
  cast(wo, wb, DD);
  gemm_bt<1><<<gg, dim3(256), 0, stream>>>(ctx, wb, d_out, B * S, D, D);
}

// Round 6
// 779.142 us; speedup vs baseline: 1.3137x; 1.2236x over previous
//
#include <hip/hip_runtime.h>
#include <hip/hip_bf16.h>
#include <cstdio>

using bf16 = __hip_bfloat16;
typedef __attribute__((ext_vector_type(8))) __bf16 bf16x8;
typedef __attribute__((ext_vector_type(4))) float f32x4;

#define DI static __device__ __forceinline__

DI f32x4 mfma16(bf16x8 a, bf16x8 b, f32x4 c) {
  return __builtin_amdgcn_mfma_f32_16x16x32_bf16(a, b, c, 0, 0, 0);
}

// async global->LDS, 16B per lane. LDS dest must be wave-uniform base (HW adds lane*16).
DI void gload16(const bf16* g, bf16* lds_base) {
  __builtin_amdgcn_global_load_lds(
      (const __attribute__((address_space(1))) unsigned int*)g,
      (__attribute__((address_space(3))) unsigned int*)lds_base,
      16, 0, 0);
}

DI bf16x8 ld8(const bf16* p) { return *(const bf16x8*)p; }

DI unsigned pack_bf16(float lo, float hi) {
  bf16 l = __float2bfloat16(lo), h = __float2bfloat16(hi);
  unsigned short ul = *(unsigned short*)&l, uh = *(unsigned short*)&h;
  return ((unsigned)uh << 16) | (unsigned)ul;
}

// ---------------- fp32 -> bf16 cast (vectorized) ----------------
__global__ __launch_bounds__(256) void cast_bf16_kernel(const float* __restrict__ in,
                                                        bf16* __restrict__ out, int n4) {
  int i = blockIdx.x * 256 + threadIdx.x;
  if (i >= n4) return;
  float4 v = reinterpret_cast<const float4*>(in)[i];
  bf16 o4[4] = {__float2bfloat16(v.x), __float2bfloat16(v.y),
                __float2bfloat16(v.z), __float2bfloat16(v.w)};
  reinterpret_cast<ushort4*>(out)[i] = *reinterpret_cast<ushort4*>(o4);
}

// ---------------- bf16 GEMM: C[M,N] = A[M,K] * B[N,K]^T ----------------
// m97 structure: 128x128 tile, BK=64, 4 waves (2x2), global_load_lds w=16,
// XOR chunk-swizzle + T1 XCD-aware block remap (8 row-panels per XCD).
template<int OUT_F32>
__global__ __launch_bounds__(256) void gemm_bt(const bf16* __restrict__ A,
                                               const bf16* __restrict__ B,
                                               void* __restrict__ Cout,
                                               int M, int N, int K) {
  __shared__ bf16 As[128 * 64];
  __shared__ bf16 Bs[128 * 64];
  const int lane = threadIdx.x & 63;
  const int wave = threadIdx.x >> 6;
  const int wm = wave >> 1, wn = wave & 1;
  // T1: bijective XCD swizzle (nwg = gridDim.x*gridDim.y, multiple of 8 here)
  const int nwg = gridDim.x * gridDim.y;
  const int cpx = nwg >> 3;
  int id = blockIdx.x + gridDim.x * blockIdx.y;
  id = (id & 7) * cpx + (id >> 3);
  const int row0 = (id / gridDim.x) * 128;
  const int col0 = (id % gridDim.x) * 128;
  const int l4 = lane >> 4, l15 = lane & 15;
  const int lr = lane >> 3, lc = lane & 7;

  f32x4 acc[4][4] = {};

  for (int k0 = 0; k0 < K; k0 += 64) {
#pragma unroll
    for (int i = 0; i < 4; ++i) {
      const int seg = wave * 4 + i;          // 16 x 1KB segments per tile
      const int r = seg * 8 + lr;            // 8 rows (128B each) per segment
      const int cg = lc ^ (r & 7);           // inverse-swizzled global chunk
      gload16(A + (size_t)(row0 + r) * K + k0 + cg * 8, As + seg * 512);
      gload16(B + (size_t)(col0 + r) * K + k0 + cg * 8, Bs + seg * 512);
    }
    __syncthreads();
#pragma unroll
    for (int kk = 0; kk < 2; ++kk) {
      bf16x8 af[4], bfr[4];
#pragma unroll
      for (int mi = 0; mi < 4; ++mi) {
        const int r = wm * 64 + mi * 16 + l15;
        const int ch = (kk * 4 + l4) ^ (r & 7);
        af[mi] = ld8(As + r * 64 + ch * 8);
      }
#pragma unroll
      for (int ni = 0; ni < 4; ++ni) {
        const int r = wn * 64 + ni * 16 + l15;
        const int ch = (kk * 4 + l4) ^ (r & 7);
        bfr[ni] = ld8(Bs + r * 64 + ch * 8);
      }
#pragma unroll
      for (int mi = 0; mi < 4; ++mi)
#pragma unroll
        for (int ni = 0; ni < 4; ++ni)
          acc[mi][ni] = mfma16(af[mi], bfr[ni], acc[mi][ni]);
    }
    __syncthreads();
  }
#pragma unroll
  for (int mi = 0; mi < 4; ++mi)
#pragma unroll
    for (int ni = 0; ni < 4; ++ni) {
      const int r0 = row0 + wm * 64 + mi * 16 + l4 * 4;
      const int c = col0 + wn * 64 + ni * 16 + l15;
#pragma unroll
      for (int j = 0; j < 4; ++j) {
        if (OUT_F32)
          ((float*)Cout)[(size_t)(r0 + j) * N + c] = acc[mi][ni][j];
        else
          ((bf16*)Cout)[(size_t)(r0 + j) * N + c] = __float2bfloat16(acc[mi][ni][j]);
      }
    }
}

// ---------------- V transpose: Vp[b,s,h*128+d] -> Vt[(b*H+h)*128+d, s] ----------------
__global__ __launch_bounds__(256) void transpose_v(const bf16* __restrict__ Vp,
                                                   bf16* __restrict__ Vt) {
  constexpr int S = 2048, D = 2048, Dk = 128;
  __shared__ bf16 t[32][33];
  const int bh = blockIdx.z;
  const int b = bh >> 4, h = bh & 15;
  const int s0 = blockIdx.x * 32, d0 = blockIdx.y * 32;
  const int tx = threadIdx.x, ty = threadIdx.y;
#pragma unroll
  for (int j = 0; j < 4; ++j)
    t[ty + j * 8][tx] = Vp[(size_t)(b * S + s0 + ty + j * 8) * D + h * Dk + d0 + tx];
  __syncthreads();
#pragma unroll
  for (int j = 0; j < 4; ++j)
    Vt[(size_t)(bh * Dk + d0 + ty + j * 8) * S + s0 + tx] = t[tx][ty + j * 8];
}

// ---------------- flash attention v3 ----------------
// v2 + T3-minimum 2-phase double-buffered K/V staging (issue next-tile
// global_load_lds before compute; single barrier per tile drains it after
// ~full-tile compute) + T1 XCD swizzle grouping 8 heads per XCD for K/V L2
// residency. grid: flat 1024 blocks, 4 waves x 32 q-rows, KVBLK=64.
__global__ __launch_bounds__(256, 2) void attn_fwd(const bf16* __restrict__ Qp,
                                                   const bf16* __restrict__ Kp,
                                                   const bf16* __restrict__ Vt,
                                                   bf16* __restrict__ ctx) {
  constexpr int S = 2048, D = 2048, Dk = 128;
  constexpr int NT = S / 64;
  constexpr float scale = 0.08838834764831845f;  // 1/sqrt(128)
  constexpr float DEFER_THR = 90.50966799187809f;  // 8/scale (raw-score domain)
  __shared__ bf16 Ks[2][64 * 128];
  __shared__ bf16 Vs[2][128 * 64];
  __shared__ bf16 Ps[4][32 * 64];
  const int lane = threadIdx.x & 63;
  const int wave = threadIdx.x >> 6;
  // T1: group the 16 q-tiles of each head (and 8 heads) on one XCD
  int id = blockIdx.x + gridDim.x * blockIdx.y;  // 0..1023
  id = (id & 7) * 128 + (id >> 3);
  const int bh = id >> 4, qt = id & 15;
  const int b = bh >> 4, h = bh & 15;
  const int l4 = lane >> 4, l15 = lane & 15;

  const bf16* Kbh = Kp + (size_t)b * S * D + h * Dk;
  const bf16* Vbh = Vt + (size_t)bh * Dk * S;

  // stage one K/V tile pair (s0 = tile start) into buffer `buf`
  auto stage = [&](int buf, int s0) {
#pragma unroll
    for (int i = 0; i < 4; ++i) {
      const int seg = wave * 4 + i;
      {  // K tile [64 s][128 dk], 4 rows (256B) per 1KB segment
        const int r = seg * 4 + l4;
        const int cg = l15 ^ (r & 7);
        gload16(Kbh + (size_t)(s0 + r) * D + cg * 8, &Ks[buf][seg * 512]);
      }
      {  // V tile [128 d][64 s], 8 rows (128B) per segment
        const int d = seg * 8 + (lane >> 3);
        const int cg = (lane & 7) ^ (d & 7);
        gload16(Vbh + (size_t)d * S + s0 + cg * 8, &Vs[buf][seg * 512]);
      }
    }
  };

  // hoist Q fragments: B-operand layout, Q[q = mi*16+l15][dk = kf*32 + l4*8 + 0..7]
  bf16x8 qf[2][4];
  {
    const bf16* Qb = Qp + (size_t)(b * S + qt * 128 + wave * 32) * D + h * Dk;
#pragma unroll
    for (int mi = 0; mi < 2; ++mi)
#pragma unroll
      for (int kf = 0; kf < 4; ++kf)
        qf[mi][kf] = ld8(Qb + (size_t)(mi * 16 + l15) * D + kf * 32 + l4 * 8);
  }

  f32x4 acc[2][8] = {};
  float mrow[2] = {-1e30f, -1e30f};  // raw-score running max for q = mi*16+l15
  float lrow[2] = {0.f, 0.f};

  bf16* Pw = &Ps[wave][0];

  stage(0, 0);
  __syncthreads();  // compiler drains vmcnt(0) before the barrier
  int cur = 0;

  for (int t = 0; t < NT; ++t) {
    if (t + 1 < NT) stage(cur ^ 1, (t + 1) * 64);  // async prefetch next tile

    // S^T = K * Q^T : sc[ni][mi] holds S[q = mi*16+l15][k = ni*16 + l4*4 + j]
    f32x4 sc[4][2] = {};
    __builtin_amdgcn_s_setprio(1);
#pragma unroll
    for (int kf = 0; kf < 4; ++kf) {
      bf16x8 kb[4];
#pragma unroll
      for (int ni = 0; ni < 4; ++ni) {
        const int r = ni * 16 + l15;
        const int ch = (kf * 4 + l4) ^ (r & 7);
        kb[ni] = ld8(&Ks[cur][r * 128 + ch * 8]);
      }
#pragma unroll
      for (int ni = 0; ni < 4; ++ni)
#pragma unroll
        for (int mi = 0; mi < 2; ++mi)
          sc[ni][mi] = mfma16(kb[ni], qf[mi][kf], sc[ni][mi]);
    }
    __builtin_amdgcn_s_setprio(0);

    // per-q tile max (raw domain): 15 in-register + 2 shuffles
    float vm[2];
#pragma unroll
    for (int mi = 0; mi < 2; ++mi) {
      float a = fmaxf(fmaxf(sc[0][mi][0], sc[0][mi][1]), fmaxf(sc[0][mi][2], sc[0][mi][3]));
#pragma unroll
      for (int ni = 1; ni < 4; ++ni) {
        a = fmaxf(a, fmaxf(fmaxf(sc[ni][mi][0], sc[ni][mi][1]),
                           fmaxf(sc[ni][mi][2], sc[ni][mi][3])));
      }
      a = fmaxf(a, __shfl_xor(a, 16));
      a = fmaxf(a, __shfl_xor(a, 32));
      vm[mi] = a;
    }

    // T13 defer-rescale: only rescale when tile max grew past threshold
    const int ok = (vm[0] - mrow[0] <= DEFER_THR) && (vm[1] - mrow[1] <= DEFER_THR);
    if (!__all(ok)) {
#pragma unroll
      for (int mi = 0; mi < 2; ++mi) {
        const float mnew = fmaxf(mrow[mi], vm[mi]);
        const float cr = __expf((mrow[mi] - mnew) * scale);
        mrow[mi] = mnew;
        lrow[mi] *= cr;
        // redistribute cr to acc's q-domain (q = mi*16 + l4*4 + j)
        float crd[4];
#pragma unroll
        for (int j = 0; j < 4; ++j) crd[j] = __shfl(cr, l4 * 4 + j);
#pragma unroll
        for (int di = 0; di < 8; ++di)
#pragma unroll
          for (int j = 0; j < 4; ++j) acc[mi][di][j] *= crd[j];
      }
    }

    // P = exp((s - m)*scale), row-sum, pack to bf16 pairs, store via ds_write_b64
#pragma unroll
    for (int mi = 0; mi < 2; ++mi) {
      const float nms = -mrow[mi] * scale;
      float rs = 0.f;
      const int q_local = mi * 16 + l15;
#pragma unroll
      for (int ni = 0; ni < 4; ++ni) {
        float p0 = __expf(fmaf(sc[ni][mi][0], scale, nms));
        float p1 = __expf(fmaf(sc[ni][mi][1], scale, nms));
        float p2 = __expf(fmaf(sc[ni][mi][2], scale, nms));
        float p3 = __expf(fmaf(sc[ni][mi][3], scale, nms));
        rs += (p0 + p1) + (p2 + p3);
        uint2 w;
        w.x = pack_bf16(p0, p1);
        w.y = pack_bf16(p2, p3);
        const int c16 = (ni * 2 + (l4 >> 1)) ^ (q_local & 7);
        *reinterpret_cast<uint2*>(Pw + q_local * 64 + c16 * 8 + (l4 & 1) * 4) = w;
      }
      rs += __shfl_xor(rs, 16);
      rs += __shfl_xor(rs, 32);
      lrow[mi] += rs;
    }

    // PV: O[q][d] += P[q][k] V[k][d]
    __builtin_amdgcn_s_setprio(1);
#pragma unroll
    for (int kk = 0; kk < 2; ++kk) {
      bf16x8 pa[2];
#pragma unroll
      for (int mi = 0; mi < 2; ++mi) {
        const int q_local = mi * 16 + l15;
        const int c = (kk * 4 + l4) ^ (q_local & 7);
        pa[mi] = ld8(Pw + q_local * 64 + c * 8);
      }
#pragma unroll
      for (int di = 0; di < 8; ++di) {
        const int r = di * 16 + l15;
        const int ch = (kk * 4 + l4) ^ (r & 7);
        const bf16x8 vb = ld8(&Vs[cur][r * 64 + ch * 8]);
#pragma unroll
        for (int mi = 0; mi < 2; ++mi)
          acc[mi][di] = mfma16(pa[mi], vb, acc[mi][di]);
      }
    }
    __builtin_amdgcn_s_setprio(0);
    __syncthreads();  // drains this iter's prefetch (issued ~full tile ago)
    cur ^= 1;
  }

  // epilogue: O = acc / l  -> ctx[b,s,h*128+d] (bf16); acc q = mi*16+l4*4+j, d = di*16+l15
#pragma unroll
  for (int mi = 0; mi < 2; ++mi) {
    float invd[4];
#pragma unroll
    for (int j = 0; j < 4; ++j) invd[j] = 1.f / __shfl(lrow[mi], l4 * 4 + j);
#pragma unroll
    for (int j = 0; j < 4; ++j) {
      const size_t base =
          (size_t)(b * S + qt * 128 + wave * 32 + mi * 16 + l4 * 4 + j) * D + h * Dk + l15;
#pragma unroll
      for (int di = 0; di < 8; ++di)
        ctx[base + di * 16] = __float2bfloat16(acc[mi][di][j] * invd[j]);
    }
  }
}

// ---------------- host orchestration ----------------
extern "C" void kernel_launch(void* const* d_in, const int* in_sizes, int n_in,
                              void* d_out, int out_size, void* d_ws, size_t ws_size,
                              hipStream_t stream) {
  constexpr int B = 4, S = 2048, D = 2048, H = 16, Dk = 128;
  constexpr size_t MD = (size_t)B * S * D;  // 16.8M elems
  constexpr size_t DD = (size_t)D * D;      // 4.2M elems

  const float* q  = (const float*)d_in[0];
  const float* k  = (const float*)d_in[1];
  const float* v  = (const float*)d_in[2];
  const float* wq = (const float*)d_in[3];
  const float* wk = (const float*)d_in[4];
  const float* wv = (const float*)d_in[5];
  const float* wo = (const float*)d_in[6];

  // Lean workspace layout (~109 MB in d_ws; Qp/Kp live inside d_out's 64 MiB,
  // both dead before the final GEMM overwrites d_out with fp32 results).
  bf16* ws = (bf16*)d_ws;
  bf16* xb = ws + 0 * MD;   // cast buffer for q/k/v (sequential), later ctx
  bf16* Vp = ws + 1 * MD;
  bf16* Vt = ws + 2 * MD;
  bf16* wb = ws + 3 * MD;   // cast buffer for wq/wk/wv/wo (sequential), DD elems
  bf16* Qp = (bf16*)d_out;  // 2*MD bf16 == 64 MiB == out_size fp32 exactly
  bf16* Kp = Qp + MD;

  const size_t need = (3 * MD + DD) * sizeof(bf16);
  if (ws_size < need)
    fprintf(stderr, "kernel_launch: ws too small (%zu < %zu)\n", ws_size, need);

  auto cast = [&](const float* src, bf16* dst, size_t n) {
    const int n4 = (int)(n / 4);
    cast_bf16_kernel<<<dim3((n4 + 255) / 256), dim3(256), 0, stream>>>(src, dst, n4);
  };
  const dim3 gg(D / 128, (B * S) / 128);

  // Q projection
  cast(q, xb, MD);
  cast(wq, wb, DD);
  gemm_bt<0><<<gg, dim3(256), 0, stream>>>(xb, wb, Qp, B * S, D, D);
  // K projection
  cast(k, xb, MD);
  cast(wk, wb, DD);
  gemm_bt<0><<<gg, dim3(256), 0, stream>>>(xb, wb, Kp, B * S, D, D);
  // V projection
  cast(v, xb, MD);
  cast(wv, wb, DD);
  gemm_bt<0><<<gg, dim3(256), 0, stream>>>(xb, wb, Vp, B * S, D, D);

  transpose_v<<<dim3(S / 32, Dk / 32, B * H), dim3(32, 8), 0, stream>>>(Vp, Vt);

  bf16* ctx = xb;
  attn_fwd<<<dim3(S / 128, B * H), dim3(256), 0, stream>>>(Qp, Kp, Vt, ctx);

  // O projection (fp32 out)
  cast(wo, wb, DD);
  gemm_bt<1><<<gg, dim3(256), 0, stream>>>(ctx, wb, d_out, B * S, D, D);
}

// Round 7
// 706.860 us; speedup vs baseline: 1.4481x; 1.1023x over previous
//
#include <hip/hip_runtime.h>
#include <hip/hip_bf16.h>
#include <cstdio>

using bf16 = __hip_bfloat16;
typedef __attribute__((ext_vector_type(8))) __bf16 bf16x8;
typedef __attribute__((ext_vector_type(4))) float f32x4;

#define DI static __device__ __forceinline__

DI f32x4 mfma16(bf16x8 a, bf16x8 b, f32x4 c) {
  return __builtin_amdgcn_mfma_f32_16x16x32_bf16(a, b, c, 0, 0, 0);
}

// async global->LDS, 16B per lane. LDS dest must be wave-uniform base (HW adds lane*16).
DI void gload16(const bf16* g, bf16* lds_base) {
  __builtin_amdgcn_global_load_lds(
      (const __attribute__((address_space(1))) unsigned int*)g,
      (__attribute__((address_space(3))) unsigned int*)lds_base,
      16, 0, 0);
}

DI bf16x8 ld8(const bf16* p) { return *(const bf16x8*)p; }

DI unsigned pack_bf16(float lo, float hi) {
  bf16 l = __float2bfloat16(lo), h = __float2bfloat16(hi);
  unsigned short ul = *(unsigned short*)&l, uh = *(unsigned short*)&h;
  return ((unsigned)uh << 16) | (unsigned)ul;
}

// ---------------- fp32 -> bf16 cast (vectorized) ----------------
__global__ __launch_bounds__(256) void cast_bf16_kernel(const float* __restrict__ in,
                                                        bf16* __restrict__ out, int n4) {
  int i = blockIdx.x * 256 + threadIdx.x;
  if (i >= n4) return;
  float4 v = reinterpret_cast<const float4*>(in)[i];
  bf16 o4[4] = {__float2bfloat16(v.x), __float2bfloat16(v.y),
                __float2bfloat16(v.z), __float2bfloat16(v.w)};
  reinterpret_cast<ushort4*>(out)[i] = *reinterpret_cast<ushort4*>(o4);
}

// ---------------- 256^2 8-phase bf16 GEMM: C[M,N] = A[M,K] * B[N,K]^T ----------------
// T2 (chunk-XOR swizzle both-sides) + T3/T4 (8 sub-phases per 2 K-tiles,
// counted vmcnt(4) once per K-tile, raw s_barrier — never __syncthreads in-loop)
// + T5 (setprio around MFMA clusters) + T1 (XCD-bijective block swizzle).
// 512 threads = 8 waves (2M x 4N); per-wave C = 128x64 = acc[8][4].
// LDS 128 KiB: [buf][op][half][128*64] bf16. A-half h = tile rows with bit6==h
// (freed by phase pair qm); B-half h = rows with bit5==h (freed by qn).
template<int OUT_F32>
__global__ __launch_bounds__(512, 2) void gemm256(const bf16* __restrict__ A,
                                                  const bf16* __restrict__ B,
                                                  void* __restrict__ Cout,
                                                  int M, int N, int K) {
  __shared__ bf16 smem[2 * 2 * 2 * 8192];  // 128 KiB
  const int lane = threadIdx.x & 63;
  const int wave = threadIdx.x >> 6;
  const int wm = wave >> 2, wn = wave & 3;
  const int l4 = lane >> 4, l15 = lane & 15;
  const int NT = K >> 6;

  // T1: bijective XCD swizzle (nwg = 256, multiple of 8)
  const int nwg = gridDim.x * gridDim.y;
  int id = blockIdx.x + gridDim.x * blockIdx.y;
  id = (id & 7) * (nwg >> 3) + (id >> 3);
  const int row0 = (id / gridDim.x) * 256;
  const int col0 = (id % gridDim.x) * 256;

  auto slab = [&](int buf, int op, int half) -> bf16* {
    return smem + (size_t)((((buf << 1) | op) << 1) | half) * 8192;
  };

  const int srow = wave * 8 + (lane >> 3);      // staging row-within-round
  const int cg = (lane & 7) ^ ((lane >> 3) & 7);  // inverse chunk swizzle

  // stage A-half h of K-tile t into buf (2 gload16/thread)
  auto stageA = [&](int buf, int h, int t) {
#pragma unroll
    for (int j = 0; j < 2; ++j) {
      const int rl = j * 64 + srow;                       // LDS row in half
      const int r = (rl & 63) + ((rl >> 6) << 7) + h * 64;  // tile row
      gload16(A + (size_t)(row0 + r) * K + t * 64 + cg * 8,
              slab(buf, 0, h) + j * 4096 + wave * 512);
    }
  };
  // stage B-half h of K-tile t into buf
  auto stageB = [&](int buf, int h, int t) {
#pragma unroll
    for (int j = 0; j < 2; ++j) {
      const int rl = j * 64 + srow;
      const int r = (rl & 31) + ((rl >> 5) << 6) + h * 32;
      gload16(B + (size_t)(col0 + r) * K + t * 64 + cg * 8,
              slab(buf, 1, h) + j * 4096 + wave * 512);
    }
  };

  f32x4 acc[8][4] = {};
  bf16x8 af[4][2], bfr[2][2];
  const int xor7 = l15 & 7;

  // ---- prologue: tile0 fully + first half-pair of tile1; wait tile0 only ----
  stageA(0, 0, 0); stageB(0, 0, 0); stageA(0, 1, 0); stageB(0, 1, 0);
  if (NT > 1) { stageA(1, 0, 1); stageB(1, 0, 1); }
  asm volatile("s_waitcnt vmcnt(4)" ::: "memory");
  __builtin_amdgcn_s_barrier();

  for (int t = 0; t < NT; ++t) {
    const int cur = t & 1;
    bf16* A0p = slab(cur, 0, 0);
    bf16* A1p = slab(cur, 0, 1);
    bf16* B0p = slab(cur, 1, 0);
    bf16* B1p = slab(cur, 1, 1);

    // ---------- phase 1: quadrant (qm=0, qn=0) ----------
#pragma unroll
    for (int mq = 0; mq < 4; ++mq)
#pragma unroll
      for (int kk = 0; kk < 2; ++kk)
        af[mq][kk] = ld8(A0p + (wm * 64 + mq * 16 + l15) * 64 +
                         (((kk * 4 + l4) ^ xor7) * 8));
#pragma unroll
    for (int nq = 0; nq < 2; ++nq)
#pragma unroll
      for (int kk = 0; kk < 2; ++kk)
        bfr[nq][kk] = ld8(B0p + (wn * 32 + nq * 16 + l15) * 64 +
                          (((kk * 4 + l4) ^ xor7) * 8));
    if (t + 1 < NT) stageA(cur ^ 1, 1, t + 1);
    __builtin_amdgcn_s_barrier();
    __builtin_amdgcn_s_setprio(1);
#pragma unroll
    for (int mq = 0; mq < 4; ++mq)
#pragma unroll
      for (int nq = 0; nq < 2; ++nq)
#pragma unroll
        for (int kk = 0; kk < 2; ++kk)
          acc[mq][nq] = mfma16(af[mq][kk], bfr[nq][kk], acc[mq][nq]);
    __builtin_amdgcn_s_setprio(0);
    __builtin_amdgcn_s_barrier();

    // ---------- phase 2: (qm=0, qn=1) — reuse af ----------
#pragma unroll
    for (int nq = 0; nq < 2; ++nq)
#pragma unroll
      for (int kk = 0; kk < 2; ++kk)
        bfr[nq][kk] = ld8(B1p + (wn * 32 + nq * 16 + l15) * 64 +
                          (((kk * 4 + l4) ^ xor7) * 8));
    if (t + 1 < NT) stageB(cur ^ 1, 1, t + 1);
    __builtin_amdgcn_s_barrier();
    __builtin_amdgcn_s_setprio(1);
#pragma unroll
    for (int mq = 0; mq < 4; ++mq)
#pragma unroll
      for (int nq = 0; nq < 2; ++nq)
#pragma unroll
        for (int kk = 0; kk < 2; ++kk)
          acc[mq][2 + nq] = mfma16(af[mq][kk], bfr[nq][kk], acc[mq][2 + nq]);
    __builtin_amdgcn_s_setprio(0);
    __builtin_amdgcn_s_barrier();

    // ---------- phase 3: (qm=1, qn=0) ----------
#pragma unroll
    for (int mq = 0; mq < 4; ++mq)
#pragma unroll
      for (int kk = 0; kk < 2; ++kk)
        af[mq][kk] = ld8(A1p + (wm * 64 + mq * 16 + l15) * 64 +
                         (((kk * 4 + l4) ^ xor7) * 8));
#pragma unroll
    for (int nq = 0; nq < 2; ++nq)
#pragma unroll
      for (int kk = 0; kk < 2; ++kk)
        bfr[nq][kk] = ld8(B0p + (wn * 32 + nq * 16 + l15) * 64 +
                          (((kk * 4 + l4) ^ xor7) * 8));
    if (t + 2 < NT) stageA(cur, 0, t + 2);  // A-half0(t) freed after phase 2
    __builtin_amdgcn_s_barrier();
    __builtin_amdgcn_s_setprio(1);
#pragma unroll
    for (int mq = 0; mq < 4; ++mq)
#pragma unroll
      for (int nq = 0; nq < 2; ++nq)
#pragma unroll
        for (int kk = 0; kk < 2; ++kk)
          acc[4 + mq][nq] = mfma16(af[mq][kk], bfr[nq][kk], acc[4 + mq][nq]);
    __builtin_amdgcn_s_setprio(0);
    __builtin_amdgcn_s_barrier();

    // ---------- phase 4: (qm=1, qn=1) ----------
#pragma unroll
    for (int nq = 0; nq < 2; ++nq)
#pragma unroll
      for (int kk = 0; kk < 2; ++kk)
        bfr[nq][kk] = ld8(B1p + (wn * 32 + nq * 16 + l15) * 64 +
                          (((kk * 4 + l4) ^ xor7) * 8));
    if (t + 2 < NT) stageB(cur, 0, t + 2);  // B-half0(t) freed after phase 3
    __builtin_amdgcn_s_barrier();
    __builtin_amdgcn_s_setprio(1);
#pragma unroll
    for (int mq = 0; mq < 4; ++mq)
#pragma unroll
      for (int nq = 0; nq < 2; ++nq)
#pragma unroll
        for (int kk = 0; kk < 2; ++kk)
          acc[4 + mq][2 + nq] = mfma16(af[mq][kk], bfr[nq][kk], acc[4 + mq][2 + nq]);
    __builtin_amdgcn_s_setprio(0);
    // counted drain: keep only this tile's ph3/ph4 stages (t+2) in flight,
    // guaranteeing all of tile t+1 has landed before its first read.
    if (t + 2 < NT) asm volatile("s_waitcnt vmcnt(4)" ::: "memory");
    else            asm volatile("s_waitcnt vmcnt(0)" ::: "memory");
    __builtin_amdgcn_s_barrier();
  }

  // ---- epilogue ----
#pragma unroll
  for (int mi = 0; mi < 8; ++mi)
#pragma unroll
    for (int ni = 0; ni < 4; ++ni) {
      const int r0 = row0 + wm * 128 + mi * 16 + l4 * 4;
      const int c = col0 + wn * 64 + ni * 16 + l15;
#pragma unroll
      for (int j = 0; j < 4; ++j) {
        if (OUT_F32)
          ((float*)Cout)[(size_t)(r0 + j) * N + c] = acc[mi][ni][j];
        else
          ((bf16*)Cout)[(size_t)(r0 + j) * N + c] = __float2bfloat16(acc[mi][ni][j]);
      }
    }
}

// ---------------- V transpose: Vp[b,s,h*128+d] -> Vt[(b*H+h)*128+d, s] ----------------
__global__ __launch_bounds__(256) void transpose_v(const bf16* __restrict__ Vp,
                                                   bf16* __restrict__ Vt) {
  constexpr int S = 2048, D = 2048, Dk = 128;
  __shared__ bf16 t[32][33];
  const int bh = blockIdx.z;
  const int b = bh >> 4, h = bh & 15;
  const int s0 = blockIdx.x * 32, d0 = blockIdx.y * 32;
  const int tx = threadIdx.x, ty = threadIdx.y;
#pragma unroll
  for (int j = 0; j < 4; ++j)
    t[ty + j * 8][tx] = Vp[(size_t)(b * S + s0 + ty + j * 8) * D + h * Dk + d0 + tx];
  __syncthreads();
#pragma unroll
  for (int j = 0; j < 4; ++j)
    Vt[(size_t)(bh * Dk + d0 + ty + j * 8) * S + s0 + tx] = t[tx][ty + j * 8];
}

// ---------------- flash attention v3 (unchanged from round 6) ----------------
__global__ __launch_bounds__(256, 2) void attn_fwd(const bf16* __restrict__ Qp,
                                                   const bf16* __restrict__ Kp,
                                                   const bf16* __restrict__ Vt,
                                                   bf16* __restrict__ ctx) {
  constexpr int S = 2048, D = 2048, Dk = 128;
  constexpr int NT = S / 64;
  constexpr float scale = 0.08838834764831845f;  // 1/sqrt(128)
  constexpr float DEFER_THR = 90.50966799187809f;  // 8/scale (raw-score domain)
  __shared__ bf16 Ks[2][64 * 128];
  __shared__ bf16 Vs[2][128 * 64];
  __shared__ bf16 Ps[4][32 * 64];
  const int lane = threadIdx.x & 63;
  const int wave = threadIdx.x >> 6;
  int id = blockIdx.x + gridDim.x * blockIdx.y;  // 0..1023
  id = (id & 7) * 128 + (id >> 3);
  const int bh = id >> 4, qt = id & 15;
  const int b = bh >> 4, h = bh & 15;
  const int l4 = lane >> 4, l15 = lane & 15;

  const bf16* Kbh = Kp + (size_t)b * S * D + h * Dk;
  const bf16* Vbh = Vt + (size_t)bh * Dk * S;

  auto stage = [&](int buf, int s0) {
#pragma unroll
    for (int i = 0; i < 4; ++i) {
      const int seg = wave * 4 + i;
      {
        const int r = seg * 4 + l4;
        const int cg = l15 ^ (r & 7);
        gload16(Kbh + (size_t)(s0 + r) * D + cg * 8, &Ks[buf][seg * 512]);
      }
      {
        const int d = seg * 8 + (lane >> 3);
        const int cg = (lane & 7) ^ (d & 7);
        gload16(Vbh + (size_t)d * S + s0 + cg * 8, &Vs[buf][seg * 512]);
      }
    }
  };

  bf16x8 qf[2][4];
  {
    const bf16* Qb = Qp + (size_t)(b * S + qt * 128 + wave * 32) * D + h * Dk;
#pragma unroll
    for (int mi = 0; mi < 2; ++mi)
#pragma unroll
      for (int kf = 0; kf < 4; ++kf)
        qf[mi][kf] = ld8(Qb + (size_t)(mi * 16 + l15) * D + kf * 32 + l4 * 8);
  }

  f32x4 acc[2][8] = {};
  float mrow[2] = {-1e30f, -1e30f};
  float lrow[2] = {0.f, 0.f};

  bf16* Pw = &Ps[wave][0];

  stage(0, 0);
  __syncthreads();
  int cur = 0;

  for (int t = 0; t < NT; ++t) {
    if (t + 1 < NT) stage(cur ^ 1, (t + 1) * 64);

    f32x4 sc[4][2] = {};
    __builtin_amdgcn_s_setprio(1);
#pragma unroll
    for (int kf = 0; kf < 4; ++kf) {
      bf16x8 kb[4];
#pragma unroll
      for (int ni = 0; ni < 4; ++ni) {
        const int r = ni * 16 + l15;
        const int ch = (kf * 4 + l4) ^ (r & 7);
        kb[ni] = ld8(&Ks[cur][r * 128 + ch * 8]);
      }
#pragma unroll
      for (int ni = 0; ni < 4; ++ni)
#pragma unroll
        for (int mi = 0; mi < 2; ++mi)
          sc[ni][mi] = mfma16(kb[ni], qf[mi][kf], sc[ni][mi]);
    }
    __builtin_amdgcn_s_setprio(0);

    float vm[2];
#pragma unroll
    for (int mi = 0; mi < 2; ++mi) {
      float a = fmaxf(fmaxf(sc[0][mi][0], sc[0][mi][1]), fmaxf(sc[0][mi][2], sc[0][mi][3]));
#pragma unroll
      for (int ni = 1; ni < 4; ++ni) {
        a = fmaxf(a, fmaxf(fmaxf(sc[ni][mi][0], sc[ni][mi][1]),
                           fmaxf(sc[ni][mi][2], sc[ni][mi][3])));
      }
      a = fmaxf(a, __shfl_xor(a, 16));
      a = fmaxf(a, __shfl_xor(a, 32));
      vm[mi] = a;
    }

    const int ok = (vm[0] - mrow[0] <= DEFER_THR) && (vm[1] - mrow[1] <= DEFER_THR);
    if (!__all(ok)) {
#pragma unroll
      for (int mi = 0; mi < 2; ++mi) {
        const float mnew = fmaxf(mrow[mi], vm[mi]);
        const float cr = __expf((mrow[mi] - mnew) * scale);
        mrow[mi] = mnew;
        lrow[mi] *= cr;
        float crd[4];
#pragma unroll
        for (int j = 0; j < 4; ++j) crd[j] = __shfl(cr, l4 * 4 + j);
#pragma unroll
        for (int di = 0; di < 8; ++di)
#pragma unroll
          for (int j = 0; j < 4; ++j) acc[mi][di][j] *= crd[j];
      }
    }

#pragma unroll
    for (int mi = 0; mi < 2; ++mi) {
      const float nms = -mrow[mi] * scale;
      float rs = 0.f;
      const int q_local = mi * 16 + l15;
#pragma unroll
      for (int ni = 0; ni < 4; ++ni) {
        float p0 = __expf(fmaf(sc[ni][mi][0], scale, nms));
        float p1 = __expf(fmaf(sc[ni][mi][1], scale, nms));
        float p2 = __expf(fmaf(sc[ni][mi][2], scale, nms));
        float p3 = __expf(fmaf(sc[ni][mi][3], scale, nms));
        rs += (p0 + p1) + (p2 + p3);
        uint2 w;
        w.x = pack_bf16(p0, p1);
        w.y = pack_bf16(p2, p3);
        const int c16 = (ni * 2 + (l4 >> 1)) ^ (q_local & 7);
        *reinterpret_cast<uint2*>(Pw + q_local * 64 + c16 * 8 + (l4 & 1) * 4) = w;
      }
      rs += __shfl_xor(rs, 16);
      rs += __shfl_xor(rs, 32);
      lrow[mi] += rs;
    }

    __builtin_amdgcn_s_setprio(1);
#pragma unroll
    for (int kk = 0; kk < 2; ++kk) {
      bf16x8 pa[2];
#pragma unroll
      for (int mi = 0; mi < 2; ++mi) {
        const int q_local = mi * 16 + l15;
        const int c = (kk * 4 + l4) ^ (q_local & 7);
        pa[mi] = ld8(Pw + q_local * 64 + c * 8);
      }
#pragma unroll
      for (int di = 0; di < 8; ++di) {
        const int r = di * 16 + l15;
        const int ch = (kk * 4 + l4) ^ (r & 7);
        const bf16x8 vb = ld8(&Vs[cur][r * 64 + ch * 8]);
#pragma unroll
        for (int mi = 0; mi < 2; ++mi)
          acc[mi][di] = mfma16(pa[mi], vb, acc[mi][di]);
      }
    }
    __builtin_amdgcn_s_setprio(0);
    __syncthreads();
    cur ^= 1;
  }

#pragma unroll
  for (int mi = 0; mi < 2; ++mi) {
    float invd[4];
#pragma unroll
    for (int j = 0; j < 4; ++j) invd[j] = 1.f / __shfl(lrow[mi], l4 * 4 + j);
#pragma unroll
    for (int j = 0; j < 4; ++j) {
      const size_t base =
          (size_t)(b * S + qt * 128 + wave * 32 + mi * 16 + l4 * 4 + j) * D + h * Dk + l15;
#pragma unroll
      for (int di = 0; di < 8; ++di)
        ctx[base + di * 16] = __float2bfloat16(acc[mi][di][j] * invd[j]);
    }
  }
}

// ---------------- host orchestration ----------------
extern "C" void kernel_launch(void* const* d_in, const int* in_sizes, int n_in,
                              void* d_out, int out_size, void* d_ws, size_t ws_size,
                              hipStream_t stream) {
  constexpr int B = 4, S = 2048, D = 2048, H = 16, Dk = 128;
  constexpr size_t MD = (size_t)B * S * D;  // 16.8M elems
  constexpr size_t DD = (size_t)D * D;      // 4.2M elems

  const float* q  = (const float*)d_in[0];
  const float* k  = (const float*)d_in[1];
  const float* v  = (const float*)d_in[2];
  const float* wq = (const float*)d_in[3];
  const float* wk = (const float*)d_in[4];
  const float* wv = (const float*)d_in[5];
  const float* wo = (const float*)d_in[6];

  bf16* ws = (bf16*)d_ws;
  bf16* xb = ws + 0 * MD;   // cast buffer for q/k/v (sequential), later ctx
  bf16* Vp = ws + 1 * MD;
  bf16* Vt = ws + 2 * MD;
  bf16* wb = ws + 3 * MD;   // cast buffer for weights (sequential), DD elems
  bf16* Qp = (bf16*)d_out;  // 2*MD bf16 == 64 MiB == out_size fp32 exactly
  bf16* Kp = Qp + MD;

  const size_t need = (3 * MD + DD) * sizeof(bf16);
  if (ws_size < need)
    fprintf(stderr, "kernel_launch: ws too small (%zu < %zu)\n", ws_size, need);

  auto cast = [&](const float* src, bf16* dst, size_t n) {
    const int n4 = (int)(n / 4);
    cast_bf16_kernel<<<dim3((n4 + 255) / 256), dim3(256), 0, stream>>>(src, dst, n4);
  };
  const dim3 gg(D / 256, (B * S) / 256);  // (8, 32) = 256 blocks, 1/CU

  // Q projection
  cast(q, xb, MD);
  cast(wq, wb, DD);
  gemm256<0><<<gg, dim3(512), 0, stream>>>(xb, wb, Qp, B * S, D, D);
  // K projection
  cast(k, xb, MD);
  cast(wk, wb, DD);
  gemm256<0><<<gg, dim3(512), 0, stream>>>(xb, wb, Kp, B * S, D, D);
  // V projection
  cast(v, xb, MD);
  cast(wv, wb, DD);
  gemm256<0><<<gg, dim3(512), 0, stream>>>(xb, wb, Vp, B * S, D, D);

  transpose_v<<<dim3(S / 32, Dk / 32, B * H), dim3(32, 8), 0, stream>>>(Vp, Vt);

  bf16* ctx = xb;
  attn_fwd<<<dim3(S / 128, B * H), dim3(256), 0, stream>>>(Qp, Kp, Vt, ctx);

  // O projection (fp32 out)
  cast(wo, wb, DD);
  gemm256<1><<<gg, dim3(512), 0, stream>>>(ctx, wb, d_out, B * S, D, D);
}